// Round 1
// baseline (960.422 us; speedup 1.0000x reference)
//
#include <hip/hip_runtime.h>

typedef __bf16 bf16x8 __attribute__((ext_vector_type(8)));
typedef float f32x4 __attribute__((ext_vector_type(4)));
typedef unsigned short u16x8 __attribute__((ext_vector_type(8)));
typedef unsigned short u16x4 __attribute__((ext_vector_type(4)));

#define DEV static __device__ __forceinline__

DEV unsigned short f2bf(float f){
  unsigned int u = __builtin_bit_cast(unsigned int, f);
  u += 0x7fffu + ((u >> 16) & 1u);
  return (unsigned short)(u >> 16);
}
DEV float bf2f(unsigned short h){
  return __builtin_bit_cast(float, ((unsigned int)h) << 16);
}
DEV float gelu_f(float x){
  float z = 0.7978845608028654f * (x + 0.044715f * x * x * x);
  float e = __expf(2.0f * z);
  float th = 1.0f - 2.0f / (e + 1.0f);
  return 0.5f * x * (1.0f + th);
}

// ---------------- weight transpose f32[R][C] -> bf16[C][R] ----------------
__global__ __launch_bounds__(256)
void transpose_cvt(const float* __restrict__ in, unsigned short* __restrict__ out,
                   int R, int C){
  __shared__ float tile[32][33];
  const int tx = threadIdx.x & 31, ty = threadIdx.x >> 5;
  const int r0 = blockIdx.y * 32, c0 = blockIdx.x * 32;
  #pragma unroll
  for (int k = 0; k < 4; ++k)
    tile[ty + k*8][tx] = in[(size_t)(r0 + ty + k*8) * C + c0 + tx];
  __syncthreads();
  #pragma unroll
  for (int k = 0; k < 4; ++k){
    int rr = ty + k*8;
    out[(size_t)(c0 + rr) * R + r0 + tx] = f2bf(tile[tx][rr]);
  }
}

__global__ __launch_bounds__(256)
void cvt_bf16_kernel(const float* __restrict__ in, unsigned short* __restrict__ out, int n){
  int i = blockIdx.x * 256 + threadIdx.x;
  if (i < n) out[i] = f2bf(in[i]);
}

// ---------------- embedding ----------------
__global__ __launch_bounds__(256)
void embed_kernel(const int* __restrict__ ids, const float* __restrict__ wte,
                  const float* __restrict__ wpe, float* __restrict__ x){
  const int m = blockIdx.x, t = threadIdx.x;
  const int id = ids[m], lpos = m & 1023;
  f32x4 a = *(const f32x4*)(wte + (size_t)id * 1024 + t*4);
  f32x4 p = *(const f32x4*)(wpe + (size_t)lpos * 1024 + t*4);
  f32x4 r = a + p;
  *(f32x4*)(x + (size_t)m * 1024 + t*4) = r;
}

// ---------------- LayerNorm: f32 in -> bf16 out ----------------
__global__ __launch_bounds__(256)
void ln_kernel(const float* __restrict__ x, const float* __restrict__ wgt,
               const float* __restrict__ bia, unsigned short* __restrict__ out){
  const int m = blockIdx.x, t = threadIdx.x;
  f32x4 v = *(const f32x4*)(x + (size_t)m * 1024 + t*4);
  float s  = v[0] + v[1] + v[2] + v[3];
  float ss = v[0]*v[0] + v[1]*v[1] + v[2]*v[2] + v[3]*v[3];
  #pragma unroll
  for (int off = 32; off >= 1; off >>= 1){
    s  += __shfl_xor(s, off);
    ss += __shfl_xor(ss, off);
  }
  __shared__ float red[8];
  if ((t & 63) == 0){ red[(t>>6)*2] = s; red[(t>>6)*2+1] = ss; }
  __syncthreads();
  float S  = red[0] + red[2] + red[4] + red[6];
  float SS = red[1] + red[3] + red[5] + red[7];
  float mean = S * (1.0f/1024.0f);
  float var  = SS * (1.0f/1024.0f) - mean*mean;
  float rstd = rsqrtf(var + 1e-5f);
  f32x4 wv = *(const f32x4*)(wgt + t*4);
  f32x4 bv = *(const f32x4*)(bia + t*4);
  u16x4 o;
  #pragma unroll
  for (int j = 0; j < 4; ++j) o[j] = f2bf(wv[j] * (v[j] - mean) * rstd + bv[j]);
  *(u16x4*)(out + (size_t)m * 1024 + t*4) = o;
}

// ---------------- after_A = h @ lA^T  (per wave: one row, 8 outputs) -------
__global__ __launch_bounds__(256)
void after_a_kernel(const unsigned short* __restrict__ hb,
                    const unsigned short* __restrict__ lab,
                    float* __restrict__ aA){
  const int t = threadIdx.x, w = t >> 6, l = t & 63;
  const int m = blockIdx.x * 4 + w;
  const unsigned short* hr = hb + (size_t)m * 1024 + l*16;
  u16x8 h0 = *(const u16x8*)(hr);
  u16x8 h1 = *(const u16x8*)(hr + 8);
  float hv[16];
  #pragma unroll
  for (int j = 0; j < 8; ++j){ hv[j] = bf2f(h0[j]); hv[8+j] = bf2f(h1[j]); }
  float s[8];
  #pragma unroll
  for (int jj = 0; jj < 8; ++jj){
    const unsigned short* ar = lab + jj*1024 + l*16;
    u16x8 a0 = *(const u16x8*)(ar);
    u16x8 a1 = *(const u16x8*)(ar + 8);
    float acc = 0.f;
    #pragma unroll
    for (int j = 0; j < 8; ++j) acc += hv[j]*bf2f(a0[j]) + hv[8+j]*bf2f(a1[j]);
    s[jj] = acc;
  }
  #pragma unroll
  for (int jj = 0; jj < 8; ++jj){
    #pragma unroll
    for (int off = 32; off >= 1; off >>= 1) s[jj] += __shfl_xor(s[jj], off);
  }
  if (l == 0){
    f32x4 o0 = {s[0], s[1], s[2], s[3]};
    f32x4 o1 = {s[4], s[5], s[6], s[7]};
    *(f32x4*)(aA + (size_t)m*8)     = o0;
    *(f32x4*)(aA + (size_t)m*8 + 4) = o1;
  }
}

// ------------- assemble Q (with dq, *0.125) and K into [B][H][L][64] -------
__global__ __launch_bounds__(256)
void assemble_qk(const float* __restrict__ qkv, const float* __restrict__ aA,
                 const float* __restrict__ lB, unsigned short* __restrict__ Qo,
                 unsigned short* __restrict__ Ko){
  const int m = blockIdx.x, t = threadIdx.x;
  const int d0 = t * 4;
  f32x4 qv  = *(const f32x4*)(qkv + (size_t)m*3072 + d0);
  f32x4 kv  = *(const f32x4*)(qkv + (size_t)m*3072 + 1024 + d0);
  f32x4 a03 = *(const f32x4*)(aA + (size_t)m*8);
  u16x4 qo, ko;
  #pragma unroll
  for (int c = 0; c < 4; ++c){
    int d = d0 + c;
    f32x4 lb = *(const f32x4*)(lB + (size_t)d*4);
    float dq = 8.0f * (a03[0]*lb[0] + a03[1]*lb[1] + a03[2]*lb[2] + a03[3]*lb[3]);
    qo[c] = f2bf((qv[c] + dq) * 0.125f);
    ko[c] = f2bf(kv[c]);
  }
  const int b = m >> 10, lpos = m & 1023, h = d0 >> 6, dh = d0 & 63;
  size_t qi = ((size_t)(b*16 + h) * 1024 + lpos) * 64 + dh;
  *(u16x4*)(Qo + qi) = qo;
  *(u16x4*)(Ko + qi) = ko;
}

// ------- assemble V (with dv) transposed into Vt [B][H][64][L] bf16 --------
__global__ __launch_bounds__(256)
void assemble_vt(const float* __restrict__ qkv, const float* __restrict__ aA,
                 const float* __restrict__ lB, unsigned short* __restrict__ Vto){
  __shared__ unsigned short vt[64 * 72];
  const int t = threadIdx.x;
  const int bh = blockIdx.y, b = bh >> 4, h = bh & 15;
  const int l0 = blockIdx.x * 64;
  {
    const int li = t >> 2, c0 = (t & 3) * 16;
    const int m = b*1024 + l0 + li;
    f32x4 a47 = *(const f32x4*)(aA + (size_t)m*8 + 4);
    #pragma unroll
    for (int cc4 = 0; cc4 < 4; ++cc4){
      f32x4 vv = *(const f32x4*)(qkv + (size_t)m*3072 + 2048 + h*64 + c0 + cc4*4);
      #pragma unroll
      for (int c = 0; c < 4; ++c){
        int dh = c0 + cc4*4 + c;
        f32x4 lb = *(const f32x4*)(lB + (size_t)(1024 + h*64 + dh)*4);
        float dv = 8.0f * (a47[0]*lb[0] + a47[1]*lb[1] + a47[2]*lb[2] + a47[3]*lb[3]);
        vt[dh*72 + li] = f2bf(vv[c] + dv);
      }
    }
  }
  __syncthreads();
  {
    const int dh = t >> 2, lc = (t & 3) * 16;
    u16x8 lo = *(const u16x8*)(&vt[dh*72 + lc]);
    u16x8 hi = *(const u16x8*)(&vt[dh*72 + lc + 8]);
    unsigned short* dst = Vto + ((size_t)(bh*64 + dh)) * 1024 + l0 + lc;
    *(u16x8*)(dst)     = lo;
    *(u16x8*)(dst + 8) = hi;
  }
}

// ---------------- GEMM: C[M][N] = A[M][K](bf16) @ Wt[N][K]^T(bf16) ----------
// MODE 0: f32 out = acc + bias
// MODE 1: f32 out = acc + bias + res
// MODE 2: bf16 out = gelu(acc + bias)
template<int MODE>
__global__ __launch_bounds__(256)
void gemm_bf16(const unsigned short* __restrict__ A,
               const unsigned short* __restrict__ Wt,
               const float* __restrict__ bias,
               const float* __restrict__ res,
               void* __restrict__ outp,
               int M, int N, int K){
  __shared__ unsigned short As[128*32];
  __shared__ unsigned short Bs[128*32];
  const int t = threadIdx.x;
  const int w = t >> 6, l = t & 63;
  const int wr = w >> 1, wc = w & 1;
  const int g = l >> 4, q = l & 15;
  const int bm = blockIdx.y * 128, bn = blockIdx.x * 128;
  const int srow = t >> 2, schunk = t & 3;
  const unsigned short* Ag = A  + (size_t)(bm + srow)*K + schunk*8;
  const unsigned short* Bg = Wt + (size_t)(bn + srow)*K + schunk*8;
  const int sa0 = srow*64        + ((schunk ^ ((srow>>1)&3)) << 4);
  const int sa1 = (srow+64)*64   + ((schunk ^ (((srow+64)>>1)&3)) << 4);
  f32x4 acc[4][4];
  #pragma unroll
  for (int m = 0; m < 4; ++m)
    #pragma unroll
    for (int n = 0; n < 4; ++n) acc[m][n] = (f32x4){0.f,0.f,0.f,0.f};
  const int nk = K >> 5;
  u16x8 ra0 = *(const u16x8*)(Ag);
  u16x8 ra1 = *(const u16x8*)(Ag + (size_t)64*K);
  u16x8 rb0 = *(const u16x8*)(Bg);
  u16x8 rb1 = *(const u16x8*)(Bg + (size_t)64*K);
  for (int kt = 0; kt < nk; ++kt){
    __syncthreads();
    *(u16x8*)((char*)As + sa0) = ra0;
    *(u16x8*)((char*)As + sa1) = ra1;
    *(u16x8*)((char*)Bs + sa0) = rb0;
    *(u16x8*)((char*)Bs + sa1) = rb1;
    __syncthreads();
    if (kt + 1 < nk){
      const unsigned short* A2 = Ag + (size_t)(kt+1)*32;
      const unsigned short* B2 = Bg + (size_t)(kt+1)*32;
      ra0 = *(const u16x8*)(A2);
      ra1 = *(const u16x8*)(A2 + (size_t)64*K);
      rb0 = *(const u16x8*)(B2);
      rb1 = *(const u16x8*)(B2 + (size_t)64*K);
    }
    bf16x8 af[4], bfr[4];
    #pragma unroll
    for (int m = 0; m < 4; ++m){
      int row = wr*64 + m*16 + q;
      af[m] = __builtin_bit_cast(bf16x8,
        *(const u16x8*)((char*)As + row*64 + ((g ^ ((row>>1)&3)) << 4)));
    }
    #pragma unroll
    for (int n = 0; n < 4; ++n){
      int row = wc*64 + n*16 + q;
      bfr[n] = __builtin_bit_cast(bf16x8,
        *(const u16x8*)((char*)Bs + row*64 + ((g ^ ((row>>1)&3)) << 4)));
    }
    #pragma unroll
    for (int m = 0; m < 4; ++m)
      #pragma unroll
      for (int n = 0; n < 4; ++n)
        acc[m][n] = __builtin_amdgcn_mfma_f32_16x16x32_bf16(af[m], bfr[n], acc[m][n], 0, 0, 0);
  }
  #pragma unroll
  for (int n = 0; n < 4; ++n){
    int col = bn + wc*64 + n*16 + q;
    float bv = bias[col];
    #pragma unroll
    for (int m = 0; m < 4; ++m){
      int row0 = bm + wr*64 + m*16 + g*4;
      #pragma unroll
      for (int r = 0; r < 4; ++r){
        int row = row0 + r;
        float v = acc[m][n][r] + bv;
        if (MODE == 1) v += res[(size_t)row*N + col];
        if (MODE == 2){
          ((unsigned short*)outp)[(size_t)row*N + col] = f2bf(gelu_f(v));
        } else {
          ((float*)outp)[(size_t)row*N + col] = v;
        }
      }
    }
  }
}

// ---------------- flash attention: 4 waves x 16 q-rows, k-tiles of 64 -------
// Q,K: [BH][1024][64] bf16 (Q pre-scaled by 1/8); Vt: [BH][64][1024] bf16
// out: [4096][1024] bf16
__global__ __launch_bounds__(256)
void attn_kernel(const unsigned short* __restrict__ Q,
                 const unsigned short* __restrict__ Kb,
                 const unsigned short* __restrict__ Vt,
                 unsigned short* __restrict__ Aout){
  __shared__ unsigned short Ks[64*64];
  __shared__ unsigned short Vs[64*64];
  const int t = threadIdx.x, w = t >> 6, l = t & 63, g = l >> 4, q = l & 15;
  const int qb = blockIdx.x, bh = blockIdx.y;
  const int b = bh >> 4, h = bh & 15;
  const size_t base = (size_t)bh * 65536;
  const int qrow = qb*64 + w*16 + q;
  bf16x8 qf0 = __builtin_bit_cast(bf16x8, *(const u16x8*)(Q + base + (size_t)qrow*64 + g*8));
  bf16x8 qf1 = __builtin_bit_cast(bf16x8, *(const u16x8*)(Q + base + (size_t)qrow*64 + 32 + g*8));
  f32x4 o[4];
  #pragma unroll
  for (int d = 0; d < 4; ++d) o[d] = (f32x4){0.f,0.f,0.f,0.f};
  float mprev = -1e30f, lsum = 0.f;
  const int srow = t >> 3, schunk = t & 7;
  const int nkt = qb + 1;
  for (int kt = 0; kt < nkt; ++kt){
    const int k0 = kt * 64;
    __syncthreads();
    #pragma unroll
    for (int it = 0; it < 2; ++it){
      int r = srow + it*32;
      u16x8 kv = *(const u16x8*)(Kb + base + (size_t)(k0 + r)*64 + schunk*8);
      *(u16x8*)((char*)Ks + r*128 + ((schunk ^ (r&7)) << 4)) = kv;
      u16x8 vv = *(const u16x8*)(Vt + base + (size_t)r*1024 + k0 + schunk*8);
      *(u16x8*)((char*)Vs + r*128 + ((schunk ^ (r&7)) << 4)) = vv;
    }
    __syncthreads();
    // St[k][q] = K @ Q^T  (swapped so scores are lane-local per q = l&15)
    f32x4 st[4];
    #pragma unroll
    for (int kf = 0; kf < 4; ++kf) st[kf] = (f32x4){0.f,0.f,0.f,0.f};
    #pragma unroll
    for (int kf = 0; kf < 4; ++kf){
      int krow = kf*16 + q;
      bf16x8 k0f = __builtin_bit_cast(bf16x8,
        *(const u16x8*)((char*)Ks + krow*128 + ((g       ^ (krow&7)) << 4)));
      bf16x8 k1f = __builtin_bit_cast(bf16x8,
        *(const u16x8*)((char*)Ks + krow*128 + (((4 + g) ^ (krow&7)) << 4)));
      st[kf] = __builtin_amdgcn_mfma_f32_16x16x32_bf16(k0f, qf0, st[kf], 0, 0, 0);
      st[kf] = __builtin_amdgcn_mfma_f32_16x16x32_bf16(k1f, qf1, st[kf], 0, 0, 0);
    }
    if (kt == nkt - 1){   // diagonal tile: causal mask (k > q -> -inf)
      #pragma unroll
      for (int kf = 0; kf < 4; ++kf)
        #pragma unroll
        for (int r = 0; r < 4; ++r){
          int kg = k0 + kf*16 + g*4 + r;
          if (kg > qrow) st[kf][r] = -1e30f;
        }
    }
    float tmax = -1e30f;
    #pragma unroll
    for (int kf = 0; kf < 4; ++kf)
      #pragma unroll
      for (int r = 0; r < 4; ++r) tmax = fmaxf(tmax, st[kf][r]);
    tmax = fmaxf(tmax, __shfl_xor(tmax, 16));
    tmax = fmaxf(tmax, __shfl_xor(tmax, 32));
    float mnew = fmaxf(mprev, tmax);
    float p[4][4]; float tsum = 0.f;
    #pragma unroll
    for (int kf = 0; kf < 4; ++kf)
      #pragma unroll
      for (int r = 0; r < 4; ++r){
        float e = __expf(st[kf][r] - mnew);
        p[kf][r] = e; tsum += e;
      }
    tsum += __shfl_xor(tsum, 16);
    tsum += __shfl_xor(tsum, 32);
    float alpha = __expf(mprev - mnew);
    lsum = lsum * alpha + tsum;
    mprev = mnew;
    float al0 = __shfl(alpha, 20*g + 0);
    float al1 = __shfl(alpha, 20*g + 1);
    float al2 = __shfl(alpha, 20*g + 2);
    float al3 = __shfl(alpha, 20*g + 3);
    #pragma unroll
    for (int d = 0; d < 4; ++d){
      o[d][0] *= al0; o[d][1] *= al1; o[d][2] *= al2; o[d][3] *= al3;
    }
    // PV: redistribute P into A-fragment layout via paired shuffles
    #pragma unroll
    for (int ks = 0; ks < 2; ++ks){
      u16x8 pau;
      #pragma unroll
      for (int j = 0; j < 8; ++j){
        int gsel = (g & 1) ? (2 + (j >> 2)) : (j >> 2);
        int src = (gsel << 4) | q;
        float v0 = __shfl(p[2*ks + 0][j & 3], src);
        float v1 = __shfl(p[2*ks + 1][j & 3], src);
        pau[j] = f2bf((g >= 2) ? v1 : v0);
      }
      bf16x8 pa = __builtin_bit_cast(bf16x8, pau);
      #pragma unroll
      for (int df = 0; df < 4; ++df){
        int vrow = df*16 + q;
        bf16x8 vf = __builtin_bit_cast(bf16x8,
          *(const u16x8*)((char*)Vs + vrow*128 + (((ks*4 + g) ^ (vrow&7)) << 4)));
        o[df] = __builtin_amdgcn_mfma_f32_16x16x32_bf16(pa, vf, o[df], 0, 0, 0);
      }
    }
  }
  float r0 = 1.f / __shfl(lsum, 20*g + 0);
  float r1 = 1.f / __shfl(lsum, 20*g + 1);
  float r2 = 1.f / __shfl(lsum, 20*g + 2);
  float r3 = 1.f / __shfl(lsum, 20*g + 3);
  const int orow0 = qb*64 + w*16 + g*4;
  #pragma unroll
  for (int df = 0; df < 4; ++df){
    int col = h*64 + df*16 + q;
    Aout[((size_t)(b*1024 + orow0 + 0))*1024 + col] = f2bf(o[df][0] * r0);
    Aout[((size_t)(b*1024 + orow0 + 1))*1024 + col] = f2bf(o[df][1] * r1);
    Aout[((size_t)(b*1024 + orow0 + 2))*1024 + col] = f2bf(o[df][2] * r2);
    Aout[((size_t)(b*1024 + orow0 + 3))*1024 + col] = f2bf(o[df][3] * r3);
  }
}

// ------------------------------- launcher ----------------------------------
extern "C" void kernel_launch(void* const* d_in, const int* in_sizes, int n_in,
                              void* d_out, int out_size, void* d_ws, size_t ws_size,
                              hipStream_t stream){
  (void)in_sizes; (void)n_in; (void)out_size; (void)ws_size;
  const int*   ids   = (const int*)  d_in[0];
  const float* wte   = (const float*)d_in[1];
  const float* wpe   = (const float*)d_in[2];
  const float* ln1w  = (const float*)d_in[3];
  const float* ln1b  = (const float*)d_in[4];
  const float* attnw = (const float*)d_in[5];
  const float* attnb = (const float*)d_in[6];
  const float* lorA  = (const float*)d_in[7];
  const float* lorB  = (const float*)d_in[8];
  const float* projw = (const float*)d_in[9];
  const float* projb = (const float*)d_in[10];
  const float* ln2w  = (const float*)d_in[11];
  const float* ln2b  = (const float*)d_in[12];
  const float* fcw   = (const float*)d_in[13];
  const float* fcb   = (const float*)d_in[14];
  const float* fc2w  = (const float*)d_in[15];
  const float* fc2b  = (const float*)d_in[16];

  char* p = (char*)d_ws;
  float* XA  = (float*)p;                    p += 16777216;   // [4096][1024] f32
  float* XB  = (float*)p;                    p += 16777216;
  unsigned short* HB  = (unsigned short*)p;  p += 8388608;    // ln1 out bf16
  unsigned short* MBf = (unsigned short*)p;  p += 8388608;    // ln2 out bf16
  float* QKV = (float*)p;                    p += 50331648;   // [4096][3072] f32
  float* AAb = (float*)p;                    p += 131072;     // [4096][8] f32
  unsigned short* Qb   = (unsigned short*)p; p += 8388608;    // [64][1024][64] bf16
  unsigned short* Kbuf = (unsigned short*)p; p += 8388608;
  unsigned short* Vtb  = (unsigned short*)p; p += 8388608;    // [64][64][1024] bf16
  unsigned short* AO   = (unsigned short*)p; p += 8388608;    // attn out bf16
  unsigned short* ACT  = (unsigned short*)p; p += 33554432;   // [4096][4096] bf16
  unsigned short* WTA  = (unsigned short*)p; p += 18874368;   // [3][3072][1024] bf16
  unsigned short* WTP  = (unsigned short*)p; p += 6291456;    // [3][1024][1024]
  unsigned short* WTF  = (unsigned short*)p; p += 25165824;   // [3][4096][1024]
  unsigned short* WTF2 = (unsigned short*)p; p += 25165824;   // [3][1024][4096]
  unsigned short* LAB  = (unsigned short*)p; p += 49152;      // [3][8][1024]

  for (int i = 0; i < 3; ++i){
    transpose_cvt<<<dim3(96, 32),  256, 0, stream>>>(attnw + (size_t)i*1024*3072, WTA  + (size_t)i*3072*1024, 1024, 3072);
    transpose_cvt<<<dim3(32, 32),  256, 0, stream>>>(projw + (size_t)i*1024*1024, WTP  + (size_t)i*1024*1024, 1024, 1024);
    transpose_cvt<<<dim3(128, 32), 256, 0, stream>>>(fcw   + (size_t)i*1024*4096, WTF  + (size_t)i*4096*1024, 1024, 4096);
    transpose_cvt<<<dim3(32, 128), 256, 0, stream>>>(fc2w  + (size_t)i*4096*1024, WTF2 + (size_t)i*1024*4096, 4096, 1024);
  }
  cvt_bf16_kernel<<<96, 256, 0, stream>>>(lorA, LAB, 24576);
  embed_kernel<<<4096, 256, 0, stream>>>(ids, wte, wpe, XA);

  for (int i = 0; i < 3; ++i){
    ln_kernel<<<4096, 256, 0, stream>>>(XA, ln1w + i*1024, ln1b + i*1024, HB);
    gemm_bf16<0><<<dim3(24, 32), 256, 0, stream>>>(HB, WTA + (size_t)i*3072*1024, attnb + i*3072, nullptr, QKV, 4096, 3072, 1024);
    after_a_kernel<<<1024, 256, 0, stream>>>(HB, LAB + i*8192, AAb);
    assemble_qk<<<4096, 256, 0, stream>>>(QKV, AAb, lorB + (size_t)i*2048*4, Qb, Kbuf);
    assemble_vt<<<dim3(16, 64), 256, 0, stream>>>(QKV, AAb, lorB + (size_t)i*2048*4, Vtb);
    attn_kernel<<<dim3(16, 64), 256, 0, stream>>>(Qb, Kbuf, Vtb, AO);
    gemm_bf16<1><<<dim3(8, 32), 256, 0, stream>>>(AO, WTP + (size_t)i*1024*1024, projb + i*1024, XA, XB, 4096, 1024, 1024);
    ln_kernel<<<4096, 256, 0, stream>>>(XB, ln2w + i*1024, ln2b + i*1024, MBf);
    gemm_bf16<2><<<dim3(32, 32), 256, 0, stream>>>(MBf, WTF + (size_t)i*4096*1024, fcb + i*4096, nullptr, ACT, 4096, 4096, 1024);
    void* xout = (i == 2) ? d_out : (void*)XA;
    gemm_bf16<1><<<dim3(8, 32), 256, 0, stream>>>(ACT, WTF2 + (size_t)i*1024*4096, fc2b + i*1024, XB, xout, 4096, 1024, 4096);
  }
}